// Round 21
// baseline (2161.108 us; speedup 1.0000x reference)
//
#include <hip/hip_runtime.h>
#include <hip/hip_bf16.h>

// Encoder: e = embed[x]; q = LSTM_q(e); k = LSTM_k(e); A = q @ k^T (per batch)
// B=32, T=512, D=512, NUM_TOKENS=14.
//
// R21 = R19 flat tag-protocol persist, tightened:
//  - speculative fetch: 32KB fetch + sentinels issued together (1 RT when
//    producers already published; verify+stale-reissue repairs early reads)
//  - per-wave gate gather: wave rt's MFMA B-rows = {gate 0..3} x {dim rt*4+dl},
//    tail gathers 4 gates via __shfl_xor(4/8/12) -> g_lds + 1 barrier deleted
//  - h_lds double-buffered -> exactly ONE __syncthreads per step
// Overwrite safety = R12 proof (publish t+2 requires verified fetch of t+1).
// qk: R18 hi/lo split bf16 MFMA. No XCD logic anywhere (R8/R20 hung; dropped).

#define TB 32
#define TT 512
#define TD 512
#define NTOK 14

typedef __attribute__((ext_vector_type(8))) short short8;
typedef __attribute__((ext_vector_type(4))) float f32x4;
typedef __attribute__((ext_vector_type(4))) unsigned int u32x4;

__device__ __forceinline__ float fsigmoid(float v) { return 1.f / (1.f + __expf(-v)); }
__device__ __forceinline__ float ftanh(float v) {
    float a = fabsf(v);
    float e = __expf(-2.f * a);
    float r = (1.f - e) / (1.f + e);
    return copysignf(r, v);
}
__device__ __forceinline__ unsigned short f2bf(float f) {
    __hip_bfloat16 h = __float2bfloat16(f);
    return __builtin_bit_cast(unsigned short, h);
}
__device__ __forceinline__ float bf2f(unsigned short u) {
    unsigned int x = ((unsigned int)u) << 16;
    return __builtin_bit_cast(float, x);
}

// device-coherent 16B load (bypass L1/L2 -> coherent point)
__device__ __forceinline__ u32x4 load16u_coh(const unsigned int* p) {
    u32x4 r;
    asm volatile("global_load_dwordx4 %0, %1, off sc0 sc1" : "=v"(r) : "v"(p));
    return r;
}
// device-coherent 4B store (write-through, fire-and-forget)
__device__ __forceinline__ void store4_coh(unsigned int* p, unsigned int v) {
    asm volatile("global_store_dword %0, %1, off sc0 sc1" :: "v"(p), "v"(v) : "memory");
}

// ---- pre_tab[l][tok][2048] = embed[tok] @ W_ih_l^T + b_ih_l + b_hh_l ----
__global__ __launch_bounds__(256) void pre_tab_kernel(
    const float* __restrict__ embed,
    const float* __restrict__ Wih_q, const float* __restrict__ bih_q, const float* __restrict__ bhh_q,
    const float* __restrict__ Wih_k, const float* __restrict__ bih_k, const float* __restrict__ bhh_k,
    float* __restrict__ pre)
{
    int idx = blockIdx.x * 256 + threadIdx.x;   // 2*14*2048 = 57344 exactly
    int l = idx / (NTOK * 4 * TD);
    int r = idx % (NTOK * 4 * TD);
    int tok = r / (4 * TD), j = r % (4 * TD);
    const float* Wih = l ? Wih_k : Wih_q;
    float acc = l ? (bih_k[j] + bhh_k[j]) : (bih_q[j] + bhh_q[j]);
    const float4* e4 = (const float4*)(embed + (size_t)tok * TD);
    const float4* w4 = (const float4*)(Wih + (size_t)j * TD);
    for (int t2 = 0; t2 < TD / 4; ++t2) {
        float4 e = e4[t2], w = w4[t2];
        acc += e.x * w.x + e.y * w.y + e.z * w.z + e.w * w.w;
    }
    pre[idx] = acc;
}

__global__ __launch_bounds__(256) void init_hbf(unsigned int* hbf) {
    hbf[blockIdx.x * 256 + threadIdx.x] = 0;    // 65536 words; tag 0 < 1
}

// ---- persistent LSTM: 128 WGs: l = wg>>6, g = (wg>>5)&1, wid = wg&31 ----
// hbf: [l][phase][b 0..31][512] u32 (bf16<<16 | step+1)
__global__ __launch_bounds__(256) void lstm_persist(
    const float* __restrict__ Whh_q, const float* __restrict__ Whh_k,
    const float* __restrict__ pre,
    const int* __restrict__ x,
    unsigned short* __restrict__ qh, unsigned short* __restrict__ ql,
    unsigned short* __restrict__ kh, unsigned short* __restrict__ kl,
    unsigned int* __restrict__ hbf)
{
    __shared__ unsigned short w_lds[64][512];     // 64 KB, XOR-swizzled chunks
    __shared__ unsigned short h_lds[2][16][512];  // 32 KB, double-buffered
    __shared__ unsigned char  x_lds[16 * TT];     // 8 KB (this group's batches)
    __shared__ float          pre_lds[NTOK][64];  // 3.5 KB [tok][gate*16+dd]

    int wg  = blockIdx.x;
    int l   = wg >> 6;
    int g   = (wg >> 5) & 1;
    int wid = wg & 31;
    int d0  = wid << 4;                          // 16 dims per WG
    int tid = threadIdx.x;
    int lane = tid & 63;
    int rt  = tid >> 6;                          // wave: dims d0 + rt*4 .. +4

    const float* Whh = l ? Whh_k : Whh_q;
    unsigned short* hi_arr = l ? kh : qh;
    unsigned short* lo_arr = l ? kl : ql;
    unsigned int* hb_l = hbf + (size_t)l * 2 * TB * TD;   // [phase][b][dim] u32

    // ---- stage W: w_lds row r = rt_r*16 + (gate*4+dl)
    //      <- W_hh row gate*TD + d0 + rt_r*4 + dl, f32->bf16, XOR swizzle ----
    {
        int r = tid >> 2;                        // 0..63, 4 threads/row
        int rt_r = r >> 4, i = r & 15;
        int gate = i >> 2, dl = i & 3;
        const float* src = Whh + (size_t)(gate * TD + d0 + rt_r * 4 + dl) * TD;
#pragma unroll
        for (int ii = 0; ii < 16; ++ii) {
            int c = (tid & 3) + 4 * ii;          // chunk 0..63 (8 bf16 = 16B)
            float4 a = ((const float4*)src)[c * 2];
            float4 b4 = ((const float4*)src)[c * 2 + 1];
            unsigned short* dst = &w_lds[r][(c ^ (r & 7)) * 8];
            dst[0] = f2bf(a.x); dst[1] = f2bf(a.y);
            dst[2] = f2bf(a.z); dst[3] = f2bf(a.w);
            dst[4] = f2bf(b4.x); dst[5] = f2bf(b4.y);
            dst[6] = f2bf(b4.z); dst[7] = f2bf(b4.w);
        }
    }
    for (int i = tid; i < 16 * TT; i += 256)
        x_lds[i] = (unsigned char)x[(g * 16 + (i >> 9)) * TT + (i & 511)];
    for (int i = tid; i < NTOK * 64; i += 256) {
        int tok = i >> 6, j = i & 63;            // j = gate*16 + dd
        pre_lds[tok][j] = pre[((size_t)l * NTOK + tok) * (4 * TD) + (j >> 4) * TD + d0 + (j & 15)];
    }
    __syncthreads();

    int dl = lane & 3;                           // tail lane's dim offset
    int dim = d0 + rt * 4 + dl;                  // global dim (tail lanes)
    float creg[4] = {0.f, 0.f, 0.f, 0.f};        // c-state (tail lanes, 4 batches)

    // ---- t = 0: tail-only on tail lanes; tagged publish; qh/ql ----
    if ((lane & 12) == 0) {
#pragma unroll
        for (int r2 = 0; r2 < 4; ++r2) {
            int bl = ((lane >> 4) << 2) + r2;
            int bg = g * 16 + bl;
            int tok = x_lds[bl * TT];
            float i_ = fsigmoid(pre_lds[tok][rt * 4 + dl]);
            float f_ = fsigmoid(pre_lds[tok][16 + rt * 4 + dl]);
            float g_ = ftanh(pre_lds[tok][32 + rt * 4 + dl]);
            float o_ = fsigmoid(pre_lds[tok][48 + rt * 4 + dl]);
            creg[r2] = i_ * g_;
            float h = o_ * ftanh(creg[r2]);
            unsigned short hh = f2bf(h);
            store4_coh(hb_l + (size_t)bg * TD + dim, ((unsigned int)hh << 16) | 1u);
            size_t hoff = ((size_t)bg * TT) * TD + dim;
            hi_arr[hoff] = hh;
            lo_arr[hoff] = f2bf(h - bf2f(hh));
        }
    }

    for (int t = 1; t < TT; ++t) {
        int buf = (t - 1) & 1;
        // ---- phase 1: speculative fetch + sentinels (1 vmcnt), verify ----
        {
            const unsigned int e = (unsigned int)t;
            int row = tid >> 4;                            // 0..15 batch in group
            const unsigned int* hb = hb_l + (size_t)buf * TB * TD
                                          + (size_t)(g * 16 + row) * TD;
            u32x4 A0[4], B0[4];
#pragma unroll
            for (int j = 0; j < 4; ++j) {
                int m = (tid & 15) + 16 * j;               // 16B-pair unit 0..63
                A0[j] = load16u_coh(hb + m * 8);
                B0[j] = load16u_coh(hb + m * 8 + 4);
            }
            int w2 = (tid & 15) * 2;
            const unsigned int* s0p = hb + w2 * 16 + 15;
            const unsigned int* s1p = hb + (w2 + 1) * 16 + 15;
            unsigned int v0, v1;
            asm volatile("global_load_dword %0, %1, off sc0 sc1" : "=v"(v0) : "v"(s0p));
            asm volatile("global_load_dword %0, %1, off sc0 sc1" : "=v"(v1) : "v"(s1p));
            asm volatile("s_waitcnt vmcnt(0)" ::: "memory");
            __builtin_amdgcn_sched_barrier(0);
            int tries = 0;
            for (;;) {                                     // sentinel gate
                if (__all(((v0 & 0xffffu) >= e) && ((v1 & 0xffffu) >= e))) break;
                if (++tries > 4) __builtin_amdgcn_s_sleep(1);
                asm volatile("global_load_dword %0, %1, off sc0 sc1" : "=v"(v0) : "v"(s0p));
                asm volatile("global_load_dword %0, %1, off sc0 sc1" : "=v"(v1) : "v"(s1p));
                asm volatile("s_waitcnt vmcnt(0)" ::: "memory");
                __builtin_amdgcn_sched_barrier(0);
            }
            // verify speculative words; reissue only stale (usually few/none)
            unsigned int st = 0xFu;
            for (;;) {
                unsigned int ns = 0;
#pragma unroll
                for (int j = 0; j < 4; ++j) if (st & (1u << j)) {
                    unsigned int bad =
                        ((A0[j].x ^ e) | (A0[j].y ^ e) | (A0[j].z ^ e) | (A0[j].w ^ e) |
                         (B0[j].x ^ e) | (B0[j].y ^ e) | (B0[j].z ^ e) | (B0[j].w ^ e)) & 0xffffu;
                    if (bad) ns |= 1u << j;
                }
                st = ns;
                if (!__any(st != 0)) break;
#pragma unroll
                for (int j = 0; j < 4; ++j) if (st & (1u << j)) {
                    int m = (tid & 15) + 16 * j;
                    A0[j] = load16u_coh(hb + m * 8);
                    B0[j] = load16u_coh(hb + m * 8 + 4);
                }
                asm volatile("s_waitcnt vmcnt(0)" ::: "memory");
                __builtin_amdgcn_sched_barrier(0);
            }
#pragma unroll
            for (int j = 0; j < 4; ++j) {                  // strip tags, pack bf16
                int m = (tid & 15) + 16 * j;
                u32x4 o;
                o.x = (A0[j].x >> 16) | (A0[j].y & 0xffff0000u);
                o.y = (A0[j].z >> 16) | (A0[j].w & 0xffff0000u);
                o.z = (B0[j].x >> 16) | (B0[j].y & 0xffff0000u);
                o.w = (B0[j].z >> 16) | (B0[j].w & 0xffff0000u);
                *(u32x4*)&h_lds[buf][row][(m ^ (row & 7)) * 8] = o;
            }
        }
        __syncthreads();                                   // ONLY barrier per step

        // ---- phase 2: MFMA, wave rt: B-rows {gate*4+dl}, K=512 ----
        f32x4 acc = {0.f, 0.f, 0.f, 0.f};
        {
            int rr = rt * 16 + (lane & 15);
            int hr = lane & 15;
#pragma unroll
            for (int kk = 0; kk < 16; ++kk) {
                int c = kk * 4 + (lane >> 4);
                short8 a  = *(const short8*)&h_lds[buf][hr][(c ^ (hr & 7)) * 8];
                short8 bf = *(const short8*)&w_lds[rr][(c ^ (rr & 7)) * 8];
                acc = __builtin_amdgcn_mfma_f32_16x16x32_bf16(a, bf, acc, 0, 0, 0);
            }
        }

        // ---- phase 3: in-wave gate gather (shfl_xor), tail, tagged publish ----
        float gfv[4], ggv[4], gov[4];
#pragma unroll
        for (int r2 = 0; r2 < 4; ++r2) {
            gfv[r2] = __shfl_xor(acc[r2], 4);
            ggv[r2] = __shfl_xor(acc[r2], 8);
            gov[r2] = __shfl_xor(acc[r2], 12);
        }
        if ((lane & 12) == 0) {
#pragma unroll
            for (int r2 = 0; r2 < 4; ++r2) {
                int bl = ((lane >> 4) << 2) + r2;
                int bg = g * 16 + bl;
                int tok = x_lds[bl * TT + t];
                float gi = acc[r2] + pre_lds[tok][rt * 4 + dl];
                float gf = gfv[r2] + pre_lds[tok][16 + rt * 4 + dl];
                float gg = ggv[r2] + pre_lds[tok][32 + rt * 4 + dl];
                float go = gov[r2] + pre_lds[tok][48 + rt * 4 + dl];
                float i_ = fsigmoid(gi), f_ = fsigmoid(gf), g2 = ftanh(gg), o_ = fsigmoid(go);
                creg[r2] = f_ * creg[r2] + i_ * g2;
                float h = o_ * ftanh(creg[r2]);
                unsigned short hh = f2bf(h);
                store4_coh(hb_l + (size_t)(t & 1) * TB * TD + (size_t)bg * TD + dim,
                           ((unsigned int)hh << 16) | (unsigned int)(t + 1));
                size_t hoff = ((size_t)bg * TT + t) * TD + dim;
                hi_arr[hoff] = hh;
                lo_arr[hoff] = f2bf(h - bf2f(hh));
            }
        }
        // no second barrier: next stage writes the OTHER h_lds buffer, and
        // barrier-ordering bounds wave skew to one phase (see header comment).
    }
}

// ---- A[b] = qh*kh^T + qh*kl^T + ql*kh^T via bf16 MFMA, 64x64 tile / WG ----
__global__ __launch_bounds__(256) void qk_mfma(
    const unsigned short* __restrict__ qh, const unsigned short* __restrict__ ql,
    const unsigned short* __restrict__ kh, const unsigned short* __restrict__ kl,
    float* __restrict__ A)
{
    __shared__ unsigned short qh_t[64][64];
    __shared__ unsigned short ql_t[64][64];
    __shared__ unsigned short kh_t[64][64];
    __shared__ unsigned short kl_t[64][64];

    int b  = blockIdx.y;
    int t0 = (blockIdx.x >> 3) * 64;
    int s0 = (blockIdx.x & 7) * 64;
    int tid = threadIdx.x;
    int lane = tid & 63;
    int w = tid >> 6;

    int tq = w * 16 + (lane & 15);
    f32x4 acc0 = {0,0,0,0}, acc1 = {0,0,0,0}, acc2 = {0,0,0,0}, acc3 = {0,0,0,0};

    for (int kc = 0; kc < 8; ++kc) {
        for (int i = tid; i < 512; i += 256) {
            int row = i >> 3, c = i & 7;
            size_t qoff = ((size_t)b * TT + t0 + row) * TD + kc * 64 + c * 8;
            size_t koff = ((size_t)b * TT + s0 + row) * TD + kc * 64 + c * 8;
            int d = (c ^ (row & 7)) * 8;
            *(short8*)&qh_t[row][d] = *(const short8*)(qh + qoff);
            *(short8*)&ql_t[row][d] = *(const short8*)(ql + qoff);
            *(short8*)&kh_t[row][d] = *(const short8*)(kh + koff);
            *(short8*)&kl_t[row][d] = *(const short8*)(kl + koff);
        }
        __syncthreads();
#pragma unroll
        for (int kk = 0; kk < 2; ++kk) {
            int c = kk * 4 + (lane >> 4);
            short8 ah = *(const short8*)&qh_t[tq][(c ^ (tq & 7)) * 8];
            short8 al = *(const short8*)&ql_t[tq][(c ^ (tq & 7)) * 8];
#pragma unroll
            for (int st = 0; st < 4; ++st) {
                int sr = st * 16 + (lane & 15);
                short8 bh = *(const short8*)&kh_t[sr][(c ^ (sr & 7)) * 8];
                short8 bl = *(const short8*)&kl_t[sr][(c ^ (sr & 7)) * 8];
                f32x4* acc = (st == 0) ? &acc0 : (st == 1) ? &acc1 : (st == 2) ? &acc2 : &acc3;
                *acc = __builtin_amdgcn_mfma_f32_16x16x32_bf16(ah, bh, *acc, 0, 0, 0);
                *acc = __builtin_amdgcn_mfma_f32_16x16x32_bf16(ah, bl, *acc, 0, 0, 0);
                *acc = __builtin_amdgcn_mfma_f32_16x16x32_bf16(al, bh, *acc, 0, 0, 0);
            }
        }
        __syncthreads();
    }
    int m = (lane >> 4) << 2;
    size_t base = (size_t)b * TT * TT + (size_t)(t0 + w * 16 + m) * TT + s0 + (lane & 15);
#pragma unroll
    for (int r2 = 0; r2 < 4; ++r2) {
        A[base + (size_t)r2 * TT +  0] = acc0[r2];
        A[base + (size_t)r2 * TT + 16] = acc1[r2];
        A[base + (size_t)r2 * TT + 32] = acc2[r2];
        A[base + (size_t)r2 * TT + 48] = acc3[r2];
    }
}

extern "C" void kernel_launch(void* const* d_in, const int* in_sizes, int n_in,
                              void* d_out, int out_size, void* d_ws, size_t ws_size,
                              hipStream_t stream)
{
    const int*   x      = (const int*)d_in[0];
    const float* embed  = (const float*)d_in[1];
    const float* Wih_q  = (const float*)d_in[2];
    const float* Whh_q  = (const float*)d_in[3];
    const float* bih_q  = (const float*)d_in[4];
    const float* bhh_q  = (const float*)d_in[5];
    const float* Wih_k  = (const float*)d_in[6];
    const float* Whh_k  = (const float*)d_in[7];
    const float* bih_k  = (const float*)d_in[8];
    const float* bhh_k  = (const float*)d_in[9];

    unsigned short* qh = (unsigned short*)d_ws;         // 8388608 us each
    unsigned short* ql = qh + (size_t)TB * TT * TD;
    unsigned short* kh = ql + (size_t)TB * TT * TD;
    unsigned short* kl = kh + (size_t)TB * TT * TD;
    float* pre = (float*)(kl + (size_t)TB * TT * TD);   // 57344 f
    unsigned int* hbf = (unsigned int*)(pre + 2 * NTOK * 4 * TD);  // 65536 u32

    init_hbf<<<256, 256, 0, stream>>>(hbf);
    pre_tab_kernel<<<224, 256, 0, stream>>>(embed, Wih_q, bih_q, bhh_q,
                                            Wih_k, bih_k, bhh_k, pre);
    lstm_persist<<<128, 256, 0, stream>>>(Whh_q, Whh_k, pre, x,
                                          qh, ql, kh, kl, hbf);
    dim3 g2(64, 32);
    qk_mfma<<<g2, 256, 0, stream>>>(qh, ql, kh, kl, (float*)d_out);
}

// Round 22
// 1483.974 us; speedup vs baseline: 1.4563x; 1.4563x over previous
//
#include <hip/hip_runtime.h>
#include <hip/hip_bf16.h>

// Encoder: e = embed[x]; q = LSTM_q(e); k = LSTM_k(e); A = q @ k^T (per batch)
// B=32, T=512, D=512, NUM_TOKENS=14.
//
// R22 = R19 verbatim (measured best: 1484 us total, persist 1435 us).
// Flat tag-protocol persist: 128 WGs = (l, batch-group g, 16-dim slice),
// one chain per WG. Publish: tagged u32 (bf16<<16 | t+1), fire-and-forget.
// Discover: 2-sentinel-per-thread sweep, then one clean 32 KB tagged fetch
// with per-word verify + stale-only reissue. Overwrite safety: R12 proof.
// qk: hi/lo split bf16 MFMA (A = qh*kh + qh*kl + ql*kh), absmax-preserving.
// Structural floor reached: 512 serial steps x ~2.8 us device-scope exchange
// (publish-visible + fetch RT); XCD-local L2 path hangs this runtime (R8/R20).

#define TB 32
#define TT 512
#define TD 512
#define NTOK 14

typedef __attribute__((ext_vector_type(8))) short short8;
typedef __attribute__((ext_vector_type(4))) float f32x4;
typedef __attribute__((ext_vector_type(4))) unsigned int u32x4;

__device__ __forceinline__ float fsigmoid(float v) { return 1.f / (1.f + __expf(-v)); }
__device__ __forceinline__ float ftanh(float v) {
    float a = fabsf(v);
    float e = __expf(-2.f * a);
    float r = (1.f - e) / (1.f + e);
    return copysignf(r, v);
}
__device__ __forceinline__ unsigned short f2bf(float f) {
    __hip_bfloat16 h = __float2bfloat16(f);
    return __builtin_bit_cast(unsigned short, h);
}
__device__ __forceinline__ float bf2f(unsigned short u) {
    unsigned int x = ((unsigned int)u) << 16;
    return __builtin_bit_cast(float, x);
}

// device-coherent 16B load (bypass L1/L2 -> reads the coherent point)
__device__ __forceinline__ u32x4 load16u_coh(const unsigned int* p) {
    u32x4 r;
    asm volatile("global_load_dwordx4 %0, %1, off sc0 sc1" : "=v"(r) : "v"(p));
    return r;
}
// device-coherent 4B store (write-through, fire-and-forget)
__device__ __forceinline__ void store4_coh(unsigned int* p, unsigned int v) {
    asm volatile("global_store_dword %0, %1, off sc0 sc1" :: "v"(p), "v"(v) : "memory");
}

// ---- pre_tab[l][tok][2048] = embed[tok] @ W_ih_l^T + b_ih_l + b_hh_l ----
__global__ __launch_bounds__(256) void pre_tab_kernel(
    const float* __restrict__ embed,
    const float* __restrict__ Wih_q, const float* __restrict__ bih_q, const float* __restrict__ bhh_q,
    const float* __restrict__ Wih_k, const float* __restrict__ bih_k, const float* __restrict__ bhh_k,
    float* __restrict__ pre)
{
    int idx = blockIdx.x * 256 + threadIdx.x;   // 2*14*2048 = 57344 exactly
    int l = idx / (NTOK * 4 * TD);
    int r = idx % (NTOK * 4 * TD);
    int tok = r / (4 * TD), j = r % (4 * TD);
    const float* Wih = l ? Wih_k : Wih_q;
    float acc = l ? (bih_k[j] + bhh_k[j]) : (bih_q[j] + bhh_q[j]);
    const float4* e4 = (const float4*)(embed + (size_t)tok * TD);
    const float4* w4 = (const float4*)(Wih + (size_t)j * TD);
    for (int t2 = 0; t2 < TD / 4; ++t2) {
        float4 e = e4[t2], w = w4[t2];
        acc += e.x * w.x + e.y * w.y + e.z * w.z + e.w * w.w;
    }
    pre[idx] = acc;
}

__global__ __launch_bounds__(256) void init_hbf(unsigned int* hbf) {
    hbf[blockIdx.x * 256 + threadIdx.x] = 0;    // 2*2*32*512 = 65536; tag 0 < 1
}

// ---- persistent LSTM: 128 WGs: l = wg>>6, g = (wg>>5)&1, wid = wg&31 ----
// hbf: [l][phase][b 0..31][512] u32 (bf16<<16 | step+1)
__global__ __launch_bounds__(256) void lstm_persist(
    const float* __restrict__ Whh_q, const float* __restrict__ Whh_k,
    const float* __restrict__ pre,
    const int* __restrict__ x,
    unsigned short* __restrict__ qh, unsigned short* __restrict__ ql,
    unsigned short* __restrict__ kh, unsigned short* __restrict__ kl,
    unsigned int* __restrict__ hbf)
{
    __shared__ unsigned short w_lds[64][512];    // 64 KB, 16B-chunk XOR swizzled
    __shared__ unsigned short h_lds[16][512];    // 16 KB, swizzled (row = batch)
    __shared__ float          g_lds[64][17];     // 4.3 KB [gate*16+dd][b_local]
    __shared__ unsigned char  x_lds[16 * TT];    // 8 KB (this group's batches)
    __shared__ float          pre_lds[NTOK][64]; // 3.5 KB [tok][gate*16+dd]

    int wg  = blockIdx.x;
    int l   = wg >> 6;
    int g   = (wg >> 5) & 1;
    int wid = wg & 31;
    int d0  = wid << 4;                          // 16 dims per WG
    int tid = threadIdx.x;
    int lane = tid & 63;
    int rt  = tid >> 6;                          // wave = gate-row tile (rows rt*16..)

    const float* Whh = l ? Whh_k : Whh_q;
    unsigned short* hi_arr = l ? kh : qh;
    unsigned short* lo_arr = l ? kl : ql;
    unsigned int* hb_l = hbf + (size_t)l * 2 * TB * TD;   // [phase][b][dim] u32

    // ---- stage W slice: 64 gate-rows (gate*16+dd), f32->bf16, XOR swizzle ----
    {
        int r = tid >> 2;                        // 0..63, 4 threads/row
        const float* src = Whh + (size_t)((r >> 4) * TD + d0 + (r & 15)) * TD;
#pragma unroll
        for (int i = 0; i < 16; ++i) {
            int c = (tid & 3) + 4 * i;           // chunk 0..63 (8 bf16 = 16B)
            float4 a = ((const float4*)src)[c * 2];
            float4 b4 = ((const float4*)src)[c * 2 + 1];
            unsigned short* dst = &w_lds[r][(c ^ (r & 7)) * 8];
            dst[0] = f2bf(a.x); dst[1] = f2bf(a.y);
            dst[2] = f2bf(a.z); dst[3] = f2bf(a.w);
            dst[4] = f2bf(b4.x); dst[5] = f2bf(b4.y);
            dst[6] = f2bf(b4.z); dst[7] = f2bf(b4.w);
        }
    }
    for (int i = tid; i < 16 * TT; i += 256)
        x_lds[i] = (unsigned char)x[(g * 16 + (i >> 9)) * TT + (i & 511)];
    for (int i = tid; i < NTOK * 64; i += 256) {
        int tok = i >> 6, j = i & 63;            // j = gate*16 + dd
        pre_lds[tok][j] = pre[((size_t)l * NTOK + tok) * (4 * TD) + (j >> 4) * TD + d0 + (j & 15)];
    }
    __syncthreads();

    int bl = tid >> 4, dd = tid & 15;            // tail mapping (16 b x 16 dd)
    int bg = g * 16 + bl;                        // global batch
    float creg = 0.f;

    // ---- t = 0: tail only (h,c = 0); tagged publish + qh/ql (no drain) ----
    {
        int tok = x_lds[bl * TT];
        float i_ = fsigmoid(pre_lds[tok][dd]);
        float f_ = fsigmoid(pre_lds[tok][16 + dd]);
        float g_ = ftanh(pre_lds[tok][32 + dd]);
        float o_ = fsigmoid(pre_lds[tok][48 + dd]);
        creg = i_ * g_;
        float h = o_ * ftanh(creg);
        unsigned short hh = f2bf(h);
        store4_coh(hb_l + (size_t)bg * TD + d0 + dd, ((unsigned int)hh << 16) | 1u);
        size_t hoff = ((size_t)bg * TT) * TD + d0 + dd;
        hi_arr[hoff] = hh;
        lo_arr[hoff] = f2bf(h - bf2f(hh));
    }

    for (int t = 1; t < TT; ++t) {
        // ---- phase 1: sentinel-gated discovery, then clean tagged fetch ----
        {
            const unsigned int e = (unsigned int)t;        // expected tag
            int row = tid >> 4;                            // 0..15 (batch in group)
            const unsigned int* hb = hb_l + (size_t)((t - 1) & 1) * TB * TD
                                          + (size_t)(g * 16 + row) * TD;
            // sentinels: this thread covers producers w2, w2+1 of its row;
            // wave-wide that is 4 rows x all 32 producers exactly.
            int w2 = (tid & 15) * 2;
            const unsigned int* s0 = hb + w2 * 16 + 15;
            const unsigned int* s1 = hb + (w2 + 1) * 16 + 15;
            for (;;) {
                unsigned int v0, v1;
                asm volatile("global_load_dword %0, %2, off sc0 sc1\n\t"
                             "global_load_dword %1, %3, off sc0 sc1\n\t"
                             "s_waitcnt vmcnt(0)"
                             : "=v"(v0), "=v"(v1) : "v"(s0), "v"(s1) : "memory");
                if (__all(((v0 & 0xffffu) >= e) && ((v1 & 0xffffu) >= e))) break;
                __builtin_amdgcn_s_sleep(1);
            }
            // full fetch with per-word verify (stale-only reissue; ~0 retries)
            u32x4 A0[4], B0[4];
#pragma unroll
            for (int j = 0; j < 4; ++j) {
                int m = (tid & 15) + 16 * j;               // 16B-pair unit 0..63
                A0[j] = load16u_coh(hb + m * 8);
                B0[j] = load16u_coh(hb + m * 8 + 4);
            }
            unsigned int st = 0xFu;
            for (;;) {
                asm volatile("s_waitcnt vmcnt(0)" ::: "memory");
                __builtin_amdgcn_sched_barrier(0);
                unsigned int ns = 0;
#pragma unroll
                for (int j = 0; j < 4; ++j) if (st & (1u << j)) {
                    unsigned int bad =
                        ((A0[j].x ^ e) | (A0[j].y ^ e) | (A0[j].z ^ e) | (A0[j].w ^ e) |
                         (B0[j].x ^ e) | (B0[j].y ^ e) | (B0[j].z ^ e) | (B0[j].w ^ e)) & 0xffffu;
                    if (bad) ns |= 1u << j;
                }
                st = ns;
                if (!__any(st != 0)) break;
#pragma unroll
                for (int j = 0; j < 4; ++j) if (st & (1u << j)) {
                    int m = (tid & 15) + 16 * j;
                    A0[j] = load16u_coh(hb + m * 8);
                    B0[j] = load16u_coh(hb + m * 8 + 4);
                }
                __builtin_amdgcn_s_sleep(1);
            }
#pragma unroll
            for (int j = 0; j < 4; ++j) {                  // strip tags, pack bf16
                int m = (tid & 15) + 16 * j;
                u32x4 o;
                o.x = (A0[j].x >> 16) | (A0[j].y & 0xffff0000u);
                o.y = (A0[j].z >> 16) | (A0[j].w & 0xffff0000u);
                o.z = (B0[j].x >> 16) | (B0[j].y & 0xffff0000u);
                o.w = (B0[j].z >> 16) | (B0[j].w & 0xffff0000u);
                *(u32x4*)&h_lds[row][(m ^ (row & 7)) * 8] = o;
            }
        }
        __syncthreads();

        // ---- phase 2: MFMA, wave rt: 16 gate-rows x 16 batches, K=512 ----
        {
            f32x4 acc = {0.f, 0.f, 0.f, 0.f};
            int rr = rt * 16 + (lane & 15);
            int hr = lane & 15;
#pragma unroll
            for (int kk = 0; kk < 16; ++kk) {
                int c = kk * 4 + (lane >> 4);
                short8 a  = *(const short8*)&h_lds[hr][(c ^ (hr & 7)) * 8];
                short8 bf = *(const short8*)&w_lds[rr][(c ^ (rr & 7)) * 8];
                acc = __builtin_amdgcn_mfma_f32_16x16x32_bf16(a, bf, acc, 0, 0, 0);
            }
            int gb = (lane >> 4) << 2;
#pragma unroll
            for (int r2 = 0; r2 < 4; ++r2) g_lds[rr][gb + r2] = acc[r2];
        }
        __syncthreads();

        // ---- phase 3: tail; tagged publish (fire-and-forget); qh/ql ----
        {
            int tok = x_lds[bl * TT + t];
            float gi = g_lds[dd][bl]      + pre_lds[tok][dd];
            float gf = g_lds[16 + dd][bl] + pre_lds[tok][16 + dd];
            float gg = g_lds[32 + dd][bl] + pre_lds[tok][32 + dd];
            float go = g_lds[48 + dd][bl] + pre_lds[tok][48 + dd];
            float i_ = fsigmoid(gi), f_ = fsigmoid(gf), g2 = ftanh(gg), o_ = fsigmoid(go);
            creg = f_ * creg + i_ * g2;
            float h = o_ * ftanh(creg);
            unsigned short hh = f2bf(h);
            store4_coh(hb_l + (size_t)(t & 1) * TB * TD + (size_t)bg * TD + d0 + dd,
                       ((unsigned int)hh << 16) | (unsigned int)(t + 1));
            size_t hoff = ((size_t)bg * TT + t) * TD + d0 + dd;
            hi_arr[hoff] = hh;                              // lazy cached stores
            lo_arr[hoff] = f2bf(h - bf2f(hh));
        }
        // no barrier: h_lds rewrite happens only after next discovery; g_lds
        // rewrite only after next phase-1 barrier (all waves past tail).
    }
}

// ---- A[b] = qh*kh^T + qh*kl^T + ql*kh^T via bf16 MFMA, 64x64 tile / WG ----
__global__ __launch_bounds__(256) void qk_mfma(
    const unsigned short* __restrict__ qh, const unsigned short* __restrict__ ql,
    const unsigned short* __restrict__ kh, const unsigned short* __restrict__ kl,
    float* __restrict__ A)
{
    __shared__ unsigned short qh_t[64][64];
    __shared__ unsigned short ql_t[64][64];
    __shared__ unsigned short kh_t[64][64];
    __shared__ unsigned short kl_t[64][64];

    int b  = blockIdx.y;
    int t0 = (blockIdx.x >> 3) * 64;
    int s0 = (blockIdx.x & 7) * 64;
    int tid = threadIdx.x;
    int lane = tid & 63;
    int w = tid >> 6;

    int tq = w * 16 + (lane & 15);
    f32x4 acc0 = {0,0,0,0}, acc1 = {0,0,0,0}, acc2 = {0,0,0,0}, acc3 = {0,0,0,0};

    for (int kc = 0; kc < 8; ++kc) {
        for (int i = tid; i < 512; i += 256) {
            int row = i >> 3, c = i & 7;
            size_t qoff = ((size_t)b * TT + t0 + row) * TD + kc * 64 + c * 8;
            size_t koff = ((size_t)b * TT + s0 + row) * TD + kc * 64 + c * 8;
            int d = (c ^ (row & 7)) * 8;
            *(short8*)&qh_t[row][d] = *(const short8*)(qh + qoff);
            *(short8*)&ql_t[row][d] = *(const short8*)(ql + qoff);
            *(short8*)&kh_t[row][d] = *(const short8*)(kh + koff);
            *(short8*)&kl_t[row][d] = *(const short8*)(kl + koff);
        }
        __syncthreads();
#pragma unroll
        for (int kk = 0; kk < 2; ++kk) {
            int c = kk * 4 + (lane >> 4);
            short8 ah = *(const short8*)&qh_t[tq][(c ^ (tq & 7)) * 8];
            short8 al = *(const short8*)&ql_t[tq][(c ^ (tq & 7)) * 8];
#pragma unroll
            for (int st = 0; st < 4; ++st) {
                int sr = st * 16 + (lane & 15);
                short8 bh = *(const short8*)&kh_t[sr][(c ^ (sr & 7)) * 8];
                short8 bl = *(const short8*)&kl_t[sr][(c ^ (sr & 7)) * 8];
                f32x4* acc = (st == 0) ? &acc0 : (st == 1) ? &acc1 : (st == 2) ? &acc2 : &acc3;
                *acc = __builtin_amdgcn_mfma_f32_16x16x32_bf16(ah, bh, *acc, 0, 0, 0);
                *acc = __builtin_amdgcn_mfma_f32_16x16x32_bf16(ah, bl, *acc, 0, 0, 0);
                *acc = __builtin_amdgcn_mfma_f32_16x16x32_bf16(al, bh, *acc, 0, 0, 0);
            }
        }
        __syncthreads();
    }
    int m = (lane >> 4) << 2;
    size_t base = (size_t)b * TT * TT + (size_t)(t0 + w * 16 + m) * TT + s0 + (lane & 15);
#pragma unroll
    for (int r2 = 0; r2 < 4; ++r2) {
        A[base + (size_t)r2 * TT +  0] = acc0[r2];
        A[base + (size_t)r2 * TT + 16] = acc1[r2];
        A[base + (size_t)r2 * TT + 32] = acc2[r2];
        A[base + (size_t)r2 * TT + 48] = acc3[r2];
    }
}

extern "C" void kernel_launch(void* const* d_in, const int* in_sizes, int n_in,
                              void* d_out, int out_size, void* d_ws, size_t ws_size,
                              hipStream_t stream)
{
    const int*   x      = (const int*)d_in[0];
    const float* embed  = (const float*)d_in[1];
    const float* Wih_q  = (const float*)d_in[2];
    const float* Whh_q  = (const float*)d_in[3];
    const float* bih_q  = (const float*)d_in[4];
    const float* bhh_q  = (const float*)d_in[5];
    const float* Wih_k  = (const float*)d_in[6];
    const float* Whh_k  = (const float*)d_in[7];
    const float* bih_k  = (const float*)d_in[8];
    const float* bhh_k  = (const float*)d_in[9];

    unsigned short* qh = (unsigned short*)d_ws;         // 8388608 us each
    unsigned short* ql = qh + (size_t)TB * TT * TD;
    unsigned short* kh = ql + (size_t)TB * TT * TD;
    unsigned short* kl = kh + (size_t)TB * TT * TD;
    float* pre = (float*)(kl + (size_t)TB * TT * TD);   // 57344 f
    unsigned int* hbf = (unsigned int*)(pre + 2 * NTOK * 4 * TD);  // 65536 u32

    init_hbf<<<256, 256, 0, stream>>>(hbf);
    pre_tab_kernel<<<224, 256, 0, stream>>>(embed, Wih_q, bih_q, bhh_q,
                                            Wih_k, bih_k, bhh_k, pre);
    lstm_persist<<<128, 256, 0, stream>>>(Whh_q, Whh_k, pre, x,
                                          qh, ql, kh, kl, hbf);
    dim3 g2(64, 32);
    qk_mfma<<<g2, 256, 0, stream>>>(qh, ql, kh, kl, (float*)d_out);
}